// Round 6
// baseline (242.506 us; speedup 1.0000x reference)
//
#include <hip/hip_runtime.h>
#include <hip/hip_bf16.h>

// RoutingLayer: B=128,S=64,N=32, D=128, K=8 capsules x C=16, 3 routing iters.
// R6: ONE WAVE PER NODE (64-thread blocks, 8192 blocks), zero barriers.
// GEMM per wave: 3 m-tiles x 8 n-tiles split-bf16 MFMA, A-frags straight from
// global (per-lane split, no cross-wave redundancy). Routing wave-synchronous
// in private LDS with s_waitcnt lgkmcnt(0) fences (DS ops are in-order per wave).

#define NB 32
#define DD 128
#define ZS 132   // zn row stride (floats)
#define PPS 37   // pp row stride (floats)

// LDS (per 64-thread block): zn 33x132 f32 + nrm 264 + pp 8x37 + uu 128 ~= 20 KB
// -> ~8 blocks/CU.

#define WSYNC() asm volatile("s_waitcnt lgkmcnt(0)" ::: "memory")

typedef __attribute__((ext_vector_type(8))) short bf16x8;
typedef __attribute__((ext_vector_type(4))) float f32x4;
typedef __attribute__((ext_vector_type(4))) float float4v;

__device__ __forceinline__ float bf16bits_to_f32(unsigned short u) {
  return __uint_as_float(((unsigned int)u) << 16);
}
__device__ __forceinline__ void split_bf16(float x, unsigned short& hi, unsigned short& lo) {
  unsigned int xb = __float_as_uint(x);
  hi = (unsigned short)(xb >> 16);
  float hif = __uint_as_float(xb & 0xFFFF0000u);
  float lof = x - hif;  // exact
  lo = (unsigned short)(__float_as_uint(lof) >> 16);
}
__device__ __forceinline__ void make_frag(float4v v0, float4v v1, bf16x8& h, bf16x8& l) {
#pragma unroll
  for (int i = 0; i < 4; ++i) {
    unsigned short hh, ll;
    split_bf16(v0[i], hh, ll);
    h[i] = (short)hh; l[i] = (short)ll;
    split_bf16(v1[i], hh, ll);
    h[4 + i] = (short)hh; l[4 + i] = (short)ll;
  }
}

__global__ void detect_kernel(const unsigned short* __restrict__ w1u,
                              int* __restrict__ flag) {
  int t = threadIdx.x;
  float v = bf16bits_to_f32(w1u[2 * t]);
  int hit = !(fabsf(v) < 1e4f);
  unsigned long long m = __ballot(hit);
  if (t == 0) flag[0] = (m != 0ull) ? 1 : 0;
}

// W (k-major 128x128) -> MFMA-B fragment-major hi/lo bf16.
__global__ __launch_bounds__(256) void swizzle_w_kernel(
    const void* __restrict__ w1, const int* __restrict__ flag,
    unsigned short* __restrict__ whi, unsigned short* __restrict__ wlo) {
  int idx = blockIdx.x * 256 + threadIdx.x;
  int k = idx >> 7, n = idx & 127;
  int kt = k >> 5, q = (k >> 3) & 3, j = k & 7;
  int nt = n >> 4, nl = n & 15;
  int lane = q * 16 + nl;
  int dst = ((kt * 8 + nt) * 64 + lane) * 8 + j;
  unsigned short hb, lb;
  if (*flag) {
    split_bf16(((const float*)w1)[idx], hb, lb);
  } else {
    hb = ((const unsigned short*)w1)[idx];
    lb = 0;
  }
  whi[dst] = hb;
  wlo[dst] = lb;
}

__global__ __launch_bounds__(64, 2) void routing_kernel(
    const void* __restrict__ selfv,
    const void* __restrict__ neighv,
    const unsigned short* __restrict__ whi,
    const unsigned short* __restrict__ wlo,
    const void* __restrict__ b1,
    void* __restrict__ out,
    const int* __restrict__ flag) {
  __shared__ __align__(16) float zn[33 * ZS];
  __shared__ __align__(16) float nrm[264];
  __shared__ __align__(16) float pp[8 * PPS];
  __shared__ __align__(16) float uu[128];

  const int lane = threadIdx.x;  // 0..63
  const int q = lane >> 4;
  const int ml = lane & 15;
  const size_t bs = blockIdx.x;
  const bool isf32 = (*flag != 0);

  const size_t noff = bs * (size_t)(NB * DD);
  const size_t soff = bs * (size_t)DD;

  // ---------------- GEMM: Z[48x128] = X @ W, split-bf16, whole GEMM per wave --
  f32x4 acc[3][8];
#pragma unroll
  for (int mt = 0; mt < 3; ++mt)
#pragma unroll
    for (int nt = 0; nt < 8; ++nt) acc[mt][nt] = (f32x4){0.f, 0.f, 0.f, 0.f};

#pragma unroll
  for (int kt = 0; kt < 4; ++kt) {
    const int col = kt * 32 + q * 8;
    bf16x8 a0h, a0l, a1h, a1l, a2h, a2l;
    if (isf32) {
      const float* nf = (const float*)neighv + noff;
      const float* sf = (const float*)selfv + soff;
      float4v v0 = *(const float4v*)(nf + (size_t)ml * DD + col);
      float4v v1 = *(const float4v*)(nf + (size_t)ml * DD + col + 4);
      make_frag(v0, v1, a0h, a0l);
      v0 = *(const float4v*)(nf + (size_t)(16 + ml) * DD + col);
      v1 = *(const float4v*)(nf + (size_t)(16 + ml) * DD + col + 4);
      make_frag(v0, v1, a1h, a1l);
      v0 = *(const float4v*)(sf + col);   // broadcast: all lanes same self row
      v1 = *(const float4v*)(sf + col + 4);
      make_frag(v0, v1, a2h, a2l);
    } else {
      const unsigned short* nbf = (const unsigned short*)neighv + noff;
      const unsigned short* sbf = (const unsigned short*)selfv + soff;
      const bf16x8 zv = (bf16x8){0, 0, 0, 0, 0, 0, 0, 0};
      a0h = *(const bf16x8*)(nbf + (size_t)ml * DD + col);
      a1h = *(const bf16x8*)(nbf + (size_t)(16 + ml) * DD + col);
      a2h = *(const bf16x8*)(sbf + col);
      a0l = zv; a1l = zv; a2l = zv;
    }
#pragma unroll
    for (int nt = 0; nt < 8; ++nt) {
      const size_t bo = ((size_t)(kt * 8 + nt) * 64 + lane) * 8;
      bf16x8 bh = *(const bf16x8*)(whi + bo);
      bf16x8 bl = *(const bf16x8*)(wlo + bo);
      acc[0][nt] = __builtin_amdgcn_mfma_f32_16x16x32_bf16(a0h, bh, acc[0][nt], 0, 0, 0);
      acc[1][nt] = __builtin_amdgcn_mfma_f32_16x16x32_bf16(a1h, bh, acc[1][nt], 0, 0, 0);
      acc[2][nt] = __builtin_amdgcn_mfma_f32_16x16x32_bf16(a2h, bh, acc[2][nt], 0, 0, 0);
      acc[0][nt] = __builtin_amdgcn_mfma_f32_16x16x32_bf16(a0h, bl, acc[0][nt], 0, 0, 0);
      acc[1][nt] = __builtin_amdgcn_mfma_f32_16x16x32_bf16(a1h, bl, acc[1][nt], 0, 0, 0);
      acc[2][nt] = __builtin_amdgcn_mfma_f32_16x16x32_bf16(a2h, bl, acc[2][nt], 0, 0, 0);
      acc[0][nt] = __builtin_amdgcn_mfma_f32_16x16x32_bf16(a0l, bh, acc[0][nt], 0, 0, 0);
      acc[1][nt] = __builtin_amdgcn_mfma_f32_16x16x32_bf16(a1l, bh, acc[1][nt], 0, 0, 0);
      acc[2][nt] = __builtin_amdgcn_mfma_f32_16x16x32_bf16(a2l, bh, acc[2][nt], 0, 0, 0);
    }
  }

  // Epilogue: bias + relu -> RAW zn (fp32) in LDS. Rows: mt0/mt1 = 0..31; mt2
  // is the broadcast self tile (all output rows equal row 32) -> write q==0,r==0.
  float bias[8];
#pragma unroll
  for (int nt = 0; nt < 8; ++nt) {
    const int c = nt * 16 + ml;
    bias[nt] = isf32 ? ((const float*)b1)[c]
                     : bf16bits_to_f32(((const unsigned short*)b1)[c]);
  }
#pragma unroll
  for (int mt = 0; mt < 2; ++mt)
#pragma unroll
    for (int nt = 0; nt < 8; ++nt)
#pragma unroll
      for (int r = 0; r < 4; ++r) {
        const int row = mt * 16 + q * 4 + r;
        zn[row * ZS + nt * 16 + ml] = fmaxf(acc[mt][nt][r] + bias[nt], 0.f);
      }
  if (q == 0) {
#pragma unroll
    for (int nt = 0; nt < 8; ++nt)
      zn[32 * ZS + nt * 16 + ml] = fmaxf(acc[2][nt][0] + bias[nt], 0.f);
  }
  WSYNC();

  // Norms per (row,k) capsule.
  for (int id = lane; id < 264; id += 64) {
    const int row = id >> 3, k = id & 7;
    const float4v* zp = (const float4v*)&zn[row * ZS + k * 16];
    float4v a = zp[0], b = zp[1], c = zp[2], d = zp[3];
    float ss = a[0]*a[0]+a[1]*a[1]+a[2]*a[2]+a[3]*a[3]
             + b[0]*b[0]+b[1]*b[1]+b[2]*b[2]+b[3]*b[3]
             + c[0]*c[0]+c[1]*c[1]+c[2]*c[2]+c[3]*c[3]
             + d[0]*d[0]+d[1]*d[1]+d[2]*d[2]+d[3]*d[3];
    nrm[id] = 1.f / fmaxf(sqrtf(ss), 1e-12f);
  }
  WSYNC();

  // ---------------- Routing: 3 iterations, wave-synchronous ----------------
  const int half = lane >> 5;        // pass2 roles
  const int k2 = (lane >> 2) & 7;
  const int c4 = lane & 3;
  const int k1 = lane & 7;           // pass1 roles
  const int ng = lane >> 3;

  for (int it = 0; it < 3; ++it) {
    if (it > 0) {
      // pass1: logits per (n,k); softmax over k; pp[k][n] = prob * nrm[n,k].
      const float4v* up = (const float4v*)&uu[k1 * 16];
      float4v U0 = up[0], U1 = up[1], U2 = up[2], U3 = up[3];
#pragma unroll
      for (int p = 0; p < 4; ++p) {
        const int n = ng + 8 * p;
        const float4v* zp = (const float4v*)&zn[n * ZS + k1 * 16];
        float4v z0 = zp[0], z1 = zp[1], z2 = zp[2], z3 = zp[3];
        float dot = U0[0]*z0[0]+U0[1]*z0[1]+U0[2]*z0[2]+U0[3]*z0[3]
                  + U1[0]*z1[0]+U1[1]*z1[1]+U1[2]*z1[2]+U1[3]*z1[3]
                  + U2[0]*z2[0]+U2[1]*z2[1]+U2[2]*z2[2]+U2[3]*z2[3]
                  + U3[0]*z3[0]+U3[1]*z3[1]+U3[2]*z3[2]+U3[3]*z3[3];
        const float nv = nrm[n * 8 + k1];
        const float lg = dot * nv;  // TAU = 1
        float m = lg;
        m = fmaxf(m, __shfl_xor(m, 1));
        m = fmaxf(m, __shfl_xor(m, 2));
        m = fmaxf(m, __shfl_xor(m, 4));
        float e = __expf(lg - m);
        float s = e;
        s += __shfl_xor(s, 1);
        s += __shfl_xor(s, 2);
        s += __shfl_xor(s, 4);
        pp[k1 * PPS + n] = (e / s) * nv;
      }
      WSYNC();
    }
    // pass2: u[k][c] = sum_n pp[k][n]*zn[n][k*16+c] + self; lanes (half,k2,c4).
    float4v a = (float4v){0.f, 0.f, 0.f, 0.f};
#pragma unroll
    for (int n0 = 0; n0 < 16; ++n0) {
      const int n = half * 16 + n0;
      const float w = (it == 0) ? nrm[n * 8 + k2] * 0.125f : pp[k2 * PPS + n];
      float4v z = *(const float4v*)&zn[n * ZS + k2 * 16 + c4 * 4];
      a[0] += w * z[0];
      a[1] += w * z[1];
      a[2] += w * z[2];
      a[3] += w * z[3];
    }
#pragma unroll
    for (int i = 0; i < 4; ++i) a[i] += __shfl_xor(a[i], 32);
    {
      float4v zs = *(const float4v*)&zn[32 * ZS + k2 * 16 + c4 * 4];
      const float sn = nrm[256 + k2];
      a[0] += sn * zs[0];
      a[1] += sn * zs[1];
      a[2] += sn * zs[2];
      a[3] += sn * zs[3];
    }
    if (it < 2) {
      float ss = a[0]*a[0] + a[1]*a[1] + a[2]*a[2] + a[3]*a[3];
      ss += __shfl_xor(ss, 1);
      ss += __shfl_xor(ss, 2);
      const float rn = 1.f / fmaxf(sqrtf(ss), 1e-12f);
      a[0] *= rn; a[1] *= rn; a[2] *= rn; a[3] *= rn;
      if (half == 0) *(float4v*)&uu[k2 * 16 + c4 * 4] = a;
      WSYNC();
    } else if (half == 0) {
      a[0] = (a[0] < 0.f) ? 0.f : a[0];
      a[1] = (a[1] < 0.f) ? 0.f : a[1];
      a[2] = (a[2] < 0.f) ? 0.f : a[2];
      a[3] = (a[3] < 0.f) ? 0.f : a[3];
      const size_t oidx = bs * DD + k2 * 16 + c4 * 4;
      if (isf32) {
        *(float4v*)((float*)out + oidx) = a;
      } else {
        unsigned int w0, w1;
        unsigned int x0 = __float_as_uint(a[0]);
        unsigned int x1 = __float_as_uint(a[1]);
        unsigned int x2 = __float_as_uint(a[2]);
        unsigned int x3 = __float_as_uint(a[3]);
        x0 += 0x7fffu + ((x0 >> 16) & 1u);
        x1 += 0x7fffu + ((x1 >> 16) & 1u);
        x2 += 0x7fffu + ((x2 >> 16) & 1u);
        x3 += 0x7fffu + ((x3 >> 16) & 1u);
        w0 = (x0 >> 16) | (x1 & 0xFFFF0000u);
        w1 = (x2 >> 16) | (x3 & 0xFFFF0000u);
        ((unsigned int*)out)[oidx / 2] = w0;
        ((unsigned int*)out)[oidx / 2 + 1] = w1;
      }
    }
  }
}

extern "C" void kernel_launch(void* const* d_in, const int* in_sizes, int n_in,
                              void* d_out, int out_size, void* d_ws, size_t ws_size,
                              hipStream_t stream) {
  (void)in_sizes; (void)n_in; (void)out_size; (void)ws_size;
  const void* selfv = d_in[0];
  const void* neighv = d_in[1];
  const void* w1 = d_in[2];
  const void* b1 = d_in[3];
  int* flag = (int*)d_ws;
  unsigned short* whi = (unsigned short*)((char*)d_ws + 64);
  unsigned short* wlo = (unsigned short*)((char*)d_ws + 64 + 32768);

  detect_kernel<<<1, 64, 0, stream>>>((const unsigned short*)w1, flag);
  swizzle_w_kernel<<<64, 256, 0, stream>>>(w1, flag, whi, wlo);
  routing_kernel<<<8192, 64, 0, stream>>>(selfv, neighv, whi, wlo, b1, d_out, flag);
}